// Round 16
// baseline (5392.481 us; speedup 1.0000x reference)
//
#include <hip/hip_runtime.h>

#define TT 1000
#define HH 512
#define G4 2048
#define SLOTS 8       // blocks per group
#define SPG 2         // seqs per group
#define HCBLK 64      // h-cols per block

typedef __attribute__((ext_vector_type(8))) short bf16x8;
typedef __attribute__((ext_vector_type(4))) float f32x4;

__device__ __forceinline__ float sigm(float v) { return 1.0f / (1.0f + __expf(-v)); }
__device__ __forceinline__ float tanh_fast(float v) { return 2.0f / (1.0f + __expf(-2.0f * v)) - 1.0f; }

__device__ __forceinline__ unsigned short bf16rne(float f) {
    unsigned u = __float_as_uint(f);
    return (unsigned short)((u + 0x7fffu + ((u >> 16) & 1u)) >> 16);
}

// One LSTM step for one chain: MFMA (K=512) + quad butterfly + gates + pack.
// Emits float4 hq0,hq1,cq0,cq1 (cols wv*8..+7 of row rowSel) valid on cc==0.
#define CHAIN_STEP(ROWS, XV, CST0, CST1, HQ0, HQ1, CQ0, CQ1) do {              \
    f32x4 acc0 = {0.f, 0.f, 0.f, 0.f};                                         \
    f32x4 acc1 = {0.f, 0.f, 0.f, 0.f};                                         \
    _Pragma("unroll")                                                          \
    for (int kt = 0; kt < 16; ++kt) {                                          \
        bf16x8 a = {0, 0, 0, 0, 0, 0, 0, 0};                                   \
        if (col < 2)                                                           \
            a = *(const bf16x8*)&(ROWS)[col][(kt * 8 + kb * 2) ^ (2 * col)];   \
        acc0 = __builtin_amdgcn_mfma_f32_16x16x32_bf16(a, breg0[kt], acc0, 0, 0, 0); \
        acc1 = __builtin_amdgcn_mfma_f32_16x16x32_bf16(a, breg1[kt], acc1, 0, 0, 0); \
    }                                                                          \
    float h1a, c1a;                                                            \
    {                                                                          \
        float v0 = acc0[0], v1 = acc0[1], v2 = acc0[2], v3 = acc0[3];          \
        float vq = q2 ? (q1 ? v3 : v2) : (q1 ? v1 : v0);                       \
        float s1 = q2 ? (q1 ? v2 : v3) : (q1 ? v0 : v1);                       \
        float s2 = q2 ? (q1 ? v1 : v0) : (q1 ? v3 : v2);                       \
        float s3 = q2 ? (q1 ? v0 : v1) : (q1 ? v2 : v3);                       \
        float g1 = __shfl_xor(s1, 1);                                          \
        float g2 = __shfl_xor(s2, 2);                                          \
        float g3 = __shfl_xor(s3, 3);                                          \
        float fv = q2 ? (q1 ? g3 : g2) : (q1 ? g1 : vq);                       \
        float iv = q2 ? (q1 ? g2 : g3) : (q1 ? vq : g1);                       \
        float ov = q2 ? (q1 ? g1 : vq) : (q1 ? g3 : g2);                       \
        float gv = q2 ? (q1 ? vq : g1) : (q1 ? g2 : g3);                       \
        fv += (XV).x * wA0[0] + (XV).y * wB0[0] + bb0[0];                      \
        iv += (XV).x * wA0[1] + (XV).y * wB0[1] + bb0[1];                      \
        ov += (XV).x * wA0[2] + (XV).y * wB0[2] + bb0[2];                      \
        gv += (XV).x * wA0[3] + (XV).y * wB0[3] + bb0[3];                      \
        c1a = sigm(fv) * (CST0) + sigm(iv) * tanh_fast(gv);                    \
        h1a = sigm(ov) * tanh_fast(c1a);                                       \
        (CST0) = c1a;                                                          \
    }                                                                          \
    float h1b, c1b;                                                            \
    {                                                                          \
        float v0 = acc1[0], v1 = acc1[1], v2 = acc1[2], v3 = acc1[3];          \
        float vq = q2 ? (q1 ? v3 : v2) : (q1 ? v1 : v0);                       \
        float s1 = q2 ? (q1 ? v2 : v3) : (q1 ? v0 : v1);                       \
        float s2 = q2 ? (q1 ? v1 : v0) : (q1 ? v3 : v2);                       \
        float s3 = q2 ? (q1 ? v0 : v1) : (q1 ? v2 : v3);                       \
        float g1 = __shfl_xor(s1, 1);                                          \
        float g2 = __shfl_xor(s2, 2);                                          \
        float g3 = __shfl_xor(s3, 3);                                          \
        float fv = q2 ? (q1 ? g3 : g2) : (q1 ? g1 : vq);                       \
        float iv = q2 ? (q1 ? g2 : g3) : (q1 ? vq : g1);                       \
        float ov = q2 ? (q1 ? g1 : vq) : (q1 ? g3 : g2);                       \
        float gv = q2 ? (q1 ? vq : g1) : (q1 ? g2 : g3);                       \
        fv += (XV).x * wA1[0] + (XV).y * wB1[0] + bb1[0];                      \
        iv += (XV).x * wA1[1] + (XV).y * wB1[1] + bb1[1];                      \
        ov += (XV).x * wA1[2] + (XV).y * wB1[2] + bb1[2];                      \
        gv += (XV).x * wA1[3] + (XV).y * wB1[3] + bb1[3];                      \
        c1b = sigm(fv) * (CST1) + sigm(iv) * tanh_fast(gv);                    \
        h1b = sigm(ov) * tanh_fast(c1b);                                       \
        (CST1) = c1b;                                                          \
    }                                                                          \
    {                                                                          \
        float ha1 = __shfl_xor(h1a, 4), ha2 = __shfl_xor(h1a, 8);              \
        float ha3 = __shfl_xor(ha1, 8);                                        \
        float hb1 = __shfl_xor(h1b, 4), hb2 = __shfl_xor(h1b, 8);              \
        float hb3 = __shfl_xor(hb1, 8);                                        \
        float ca1 = __shfl_xor(c1a, 4), ca2 = __shfl_xor(c1a, 8);              \
        float ca3 = __shfl_xor(ca1, 8);                                        \
        float cb1 = __shfl_xor(c1b, 4), cb2 = __shfl_xor(c1b, 8);              \
        float cb3 = __shfl_xor(cb1, 8);                                        \
        (HQ0) = (float4){h1a, ha1, ha2, ha3};                                  \
        (HQ1) = (float4){h1b, hb1, hb2, hb3};                                  \
        (CQ0) = (float4){c1a, ca1, ca2, ca3};                                  \
        (CQ1) = (float4){c1b, cb1, cb2, cb3};                                  \
    }                                                                          \
} while (0)

// 256 blocks x 512 thr (8 waves, 1/CU). TWO chains per block: block b serves
// slot s=b>>5 of group gA=b&31 AND group gB=gA+32 (64 groups x 2 seqs; same
// 64 h-cols -> same weight registers). Per superstep the two exchanges run
// CONCURRENTLY: compute A, fire A stores, compute B (A visibility propagates
// underneath), fire B, one shared ack, both flags, one combined 16-line poll,
// one combined refill (exactly 1 u64/thread). Protocol = R11 flag-guarantee;
// LDS = R12-15 conflict-free [2][132]+XOR layout.
__global__ __launch_bounds__(512, 1)
void lstm_2c(const float* __restrict__ x,     // [B][T][2]
             const float* __restrict__ wih,   // [2][4H]
             const float* __restrict__ whh,   // [H][4H]
             const float* __restrict__ bias,  // [4H]
             float* __restrict__ out,         // h [B][T][H] then c [B][T][H]
             float* ws)
{
    __shared__ unsigned long long ldsA[2][2][2][132];   // [chain][buf][row][u64]

    const int bid  = blockIdx.x;
    const int gA   = bid & 31;
    const int slot = bid >> 5;
    const int gB   = gA + 32;
    const int tid  = threadIdx.x;
    const int wv   = tid >> 6;             // 0..7
    const int lane = tid & 63;
    const int col  = lane & 15;
    const int kb   = lane >> 4;            // 0..3
    const int q    = col & 3;              // gate id 0=f,1=i,2=o,3=g
    const int q1   = q & 1, q2 = q >> 1;
    const int cc   = col >> 2;             // within-tile h-col 0..3
    const int hc0  = slot * HCBLK + wv * 8 + cc;
    const int hc1  = hc0 + 4;
    const int rowSel = kb * 4 + q;         // valid rows: 0..1
    const int row2 = rowSel & 1;
    const int bA   = gA * SPG + row2;      // chain-A batch index (clamped)
    const int bB   = gB * SPG + row2;      // chain-B batch index
    const bool storer = (kb == 0) && (cc == 0) && (q < 2);

    unsigned long long* slab = (unsigned long long*)ws;      // u64[2][128][128]
    unsigned* flags = (unsigned*)((char*)ws + 256 * 1024);   // 512 lines x 64B

    // zero all LDS buffers (buf0 of both chains = h(0) = 0)
    for (int i = tid; i < 2 * 2 * 2 * 132; i += 512)
        ((unsigned long long*)ldsA)[i] = 0ULL;

    // ---- one-time: W_hh fragments into registers (shared by both chains) ----
    const int gc0 = q * 512 + hc0;
    const int gc1 = q * 512 + hc1;
    bf16x8 breg0[16], breg1[16];
    #pragma unroll
    for (int kt = 0; kt < 16; ++kt) {
        bf16x8 f0, f1;
        #pragma unroll
        for (int j = 0; j < 8; ++j) {
            int k = kt * 32 + kb * 8 + j;
            f0[j] = (short)bf16rne(whh[(size_t)k * G4 + gc0]);
            f1[j] = (short)bf16rne(whh[(size_t)k * G4 + gc1]);
        }
        breg0[kt] = f0;
        breg1[kt] = f1;
    }

    float wA0[4], wB0[4], bb0[4], wA1[4], wB1[4], bb1[4];
    #pragma unroll
    for (int j = 0; j < 4; ++j) {
        int a0 = j * 512 + hc0, a1 = j * 512 + hc1;
        wA0[j] = wih[a0]; wB0[j] = wih[G4 + a0]; bb0[j] = bias[a0];
        wA1[j] = wih[a1]; wB1[j] = wih[G4 + a1]; bb1[j] = bias[a1];
    }

    float cstA0 = 0.f, cstA1 = 0.f, cstB0 = 0.f, cstB1 = 0.f;
    const size_t OSZ = (size_t)128 * TT * HH;
    const float* xpA = x + (size_t)bA * TT * 2;
    const float* xpB = x + (size_t)bB * TT * 2;
    float2 xvA = *(const float2*)(xpA);
    float2 xvB = *(const float2*)(xpB);

    // combined-refill mapping: 512 threads <-> 2 chains x 2 rows x 128 u64
    const int rch  = tid >> 8;             // chain 0=A, 1=B
    const int crow = (tid >> 7) & 1;       // row within group
    const int ck   = tid & 127;            // u64 within row
    const int srcRow = (rch == 0 ? gA : gB) * SPG + crow;   // global seq

    __syncthreads();

    for (int t = 0; t < TT; ++t) {
        const int rb = t & 1;
        const unsigned tag = (unsigned)(t + 1);
        const int phase = (t + 1) & 1;
        float4 hqA0, hqA1, cqA0, cqA1, hqB0, hqB1, cqB0, cqB1;

        // ---- chain A step; fire its slab stores immediately ----
        CHAIN_STEP(ldsA[0][rb], xvA, cstA0, cstA1, hqA0, hqA1, cqA0, cqA1);
        if (t + 1 < TT && storer) {
            unsigned long long w0 =
                  (unsigned long long)bf16rne(hqA0.x)
                | ((unsigned long long)bf16rne(hqA0.y) << 16)
                | ((unsigned long long)bf16rne(hqA0.z) << 32)
                | ((unsigned long long)bf16rne(hqA0.w) << 48);
            unsigned long long w1 =
                  (unsigned long long)bf16rne(hqA1.x)
                | ((unsigned long long)bf16rne(hqA1.y) << 16)
                | ((unsigned long long)bf16rne(hqA1.z) << 32)
                | ((unsigned long long)bf16rne(hqA1.w) << 48);
            unsigned long long* dst = slab
                + ((size_t)(phase * 128 + bA)) * 128 + slot * 16 + wv * 2;
            __hip_atomic_store(dst,     w0, __ATOMIC_RELAXED, __HIP_MEMORY_SCOPE_AGENT);
            __hip_atomic_store(dst + 1, w1, __ATOMIC_RELAXED, __HIP_MEMORY_SCOPE_AGENT);
        }

        // ---- chain B step (A's store visibility propagates underneath) ----
        CHAIN_STEP(ldsA[1][rb], xvB, cstB0, cstB1, hqB0, hqB1, cqB0, cqB1);
        if (t + 1 < TT && storer) {
            unsigned long long w0 =
                  (unsigned long long)bf16rne(hqB0.x)
                | ((unsigned long long)bf16rne(hqB0.y) << 16)
                | ((unsigned long long)bf16rne(hqB0.z) << 32)
                | ((unsigned long long)bf16rne(hqB0.w) << 48);
            unsigned long long w1 =
                  (unsigned long long)bf16rne(hqB1.x)
                | ((unsigned long long)bf16rne(hqB1.y) << 16)
                | ((unsigned long long)bf16rne(hqB1.z) << 32)
                | ((unsigned long long)bf16rne(hqB1.w) << 48);
            unsigned long long* dst = slab
                + ((size_t)(phase * 128 + bB)) * 128 + slot * 16 + wv * 2;
            __hip_atomic_store(dst,     w0, __ATOMIC_RELAXED, __HIP_MEMORY_SCOPE_AGENT);
            __hip_atomic_store(dst + 1, w1, __ATOMIC_RELAXED, __HIP_MEMORY_SCOPE_AGENT);
        }

        if (t + 1 < TT) {
            // shared ack: both chains' slab stores globally visible
            asm volatile("s_waitcnt vmcnt(0)" ::: "memory");
            asm volatile("s_barrier" ::: "memory");

            // both flags = guarantee
            if (tid == 0) {
                __hip_atomic_store(&flags[(gA * SLOTS + slot) * 16], tag,
                                   __ATOMIC_RELAXED, __HIP_MEMORY_SCOPE_AGENT);
                __hip_atomic_store(&flags[(gB * SLOTS + slot) * 16], tag,
                                   __ATOMIC_RELAXED, __HIP_MEMORY_SCOPE_AGENT);
            }

            // out flush both chains (fire-and-forget; drained by next ack)
            if (storer) {
                size_t oA = ((size_t)bA * TT + t) * HH + slot * HCBLK + wv * 8;
                *(float4*)(out + oA)           = hqA0;
                *(float4*)(out + oA + 4)       = hqA1;
                *(float4*)(out + OSZ + oA)     = cqA0;
                *(float4*)(out + OSZ + oA + 4) = cqA1;
                size_t oB = ((size_t)bB * TT + t) * HH + slot * HCBLK + wv * 8;
                *(float4*)(out + oB)           = hqB0;
                *(float4*)(out + oB + 4)       = hqB1;
                *(float4*)(out + OSZ + oB)     = cqB0;
                *(float4*)(out + OSZ + oB + 4) = cqB1;
            }

            xvA = *(const float2*)(xpA + 2 * (t + 1));
            xvB = *(const float2*)(xpB + 2 * (t + 1));

            // ---- combined poll: 16 flag lines (both chains), all waves ----
            {
                long gd = 0;
                for (;;) {
                    unsigned fl = tag;
                    if (lane < 16) {
                        int gx = (lane < 8) ? gA : gB;
                        fl = __hip_atomic_load(&flags[(gx * SLOTS + (lane & 7)) * 16],
                                               __ATOMIC_RELAXED, __HIP_MEMORY_SCOPE_AGENT);
                    }
                    if (__all(fl >= tag)) break;
                    __builtin_amdgcn_s_sleep(1);
                    if (++gd > 20000000L) break;   // anti-hang escape
                }
            }

            // ---- combined refill: exactly 1 u64 per thread ----
            const unsigned long long* myp = slab
                + ((size_t)(phase * 128 + srcRow)) * 128 + ck;
            unsigned long long d = __hip_atomic_load(myp, __ATOMIC_RELAXED,
                                                     __HIP_MEMORY_SCOPE_AGENT);
            ldsA[rch][phase][crow][ck ^ (2 * crow)] = d;

            asm volatile("s_waitcnt lgkmcnt(0)\n\ts_barrier" ::: "memory");
        } else {
            if (storer) {
                size_t oA = ((size_t)bA * TT + t) * HH + slot * HCBLK + wv * 8;
                *(float4*)(out + oA)           = hqA0;
                *(float4*)(out + oA + 4)       = hqA1;
                *(float4*)(out + OSZ + oA)     = cqA0;
                *(float4*)(out + OSZ + oA + 4) = cqA1;
                size_t oB = ((size_t)bB * TT + t) * HH + slot * HCBLK + wv * 8;
                *(float4*)(out + oB)           = hqB0;
                *(float4*)(out + oB + 4)       = hqB1;
                *(float4*)(out + OSZ + oB)     = cqB0;
                *(float4*)(out + OSZ + oB + 4) = cqB1;
            }
        }
    }
}

extern "C" void kernel_launch(void* const* d_in, const int* in_sizes, int n_in,
                              void* d_out, int out_size, void* d_ws, size_t ws_size,
                              hipStream_t stream) {
    const float* x    = (const float*)d_in[0];
    const float* wih  = (const float*)d_in[1];
    const float* whh  = (const float*)d_in[2];
    const float* bias = (const float*)d_in[3];
    float* out = (float*)d_out;
    float* ws  = (float*)d_ws;

    // zero the 512 flag lines every launch (slab is flag-guarded)
    hipMemsetAsync((char*)d_ws + 256 * 1024, 0, 512 * 16 * sizeof(unsigned), stream);

    dim3 grid(256), block(512);
    hipLaunchKernelGGL(lstm_2c, grid, block, 0, stream, x, wih, whh, bias, out, ws);
}